// Round 10
// baseline (269.186 us; speedup 1.0000x reference)
//
#include <hip/hip_runtime.h>
#include <hip/hip_bf16.h>

#define T_TOKENS 2048
#define DIM 256
#define NLEV 8

using bf16x8 = __attribute__((ext_vector_type(8))) short;
using f32x4  = __attribute__((ext_vector_type(4))) float;

__device__ __forceinline__ unsigned short f2bf(float f) {
    union { float f; unsigned u; } v; v.f = f;
    unsigned r = v.u + 0x7FFFu + ((v.u >> 16) & 1u);   // RNE
    return (unsigned short)(r >> 16);
}

// ---------------- Kernel 1: routing (exact fp32) + x -> bf16 conversion ----------------
__global__ __launch_bounds__(256) void route_kernel(
    const float* __restrict__ x, const float* __restrict__ w1s,
    const float* __restrict__ b1s,
    float* __restrict__ pw,            // [T][8]
    int*   __restrict__ pc,            // [T] pathcode in [256,511]
    unsigned short* __restrict__ xbf)  // [T][256] bf16
{
    int wave = threadIdx.x >> 6;
    int lane = threadIdx.x & 63;
    int t = blockIdx.x * 4 + wave;    // grid = 512 -> t < 2048

    const float4 xv = *reinterpret_cast<const float4*>(x + (size_t)t * DIM + lane * 4);

    // emit bf16 copy of x (coalesced 8B/lane)
    ushort4 xb;
    xb.x = f2bf(xv.x); xb.y = f2bf(xv.y); xb.z = f2bf(xv.z); xb.w = f2bf(xv.w);
    *reinterpret_cast<ushort4*>(xbf + (size_t)t * DIM + lane * 4) = xb;

    int p = 1;
    float keep = 0.0f;
    #pragma unroll
    for (int lvl = 0; lvl < NLEV; ++lvl) {
        int node = p - 1;
        const float4 wv = *reinterpret_cast<const float4*>(w1s + (size_t)node * DIM + lane * 4);
        float s = xv.x * wv.x + xv.y * wv.y + xv.z * wv.z + xv.w * wv.w;
        #pragma unroll
        for (int off = 32; off; off >>= 1) s += __shfl_xor(s, off);
        float score = s + b1s[node];
        float a = fabsf(score);
        float g = a * 0.5f * (1.0f + erff(a * 0.70710678118654752f));  // exact GELU
        if (lane == lvl) keep = g;
        int choice = (score > 0.0f) ? 1 : 0;   // sign(0)->choice 0 matches ref
        p = 2 * p + choice;
    }
    if (lane < NLEV) pw[(size_t)t * NLEV + lane] = keep;
    if (lane == 0) pc[t] = p;
}

// ---------------- Kernel 2: counting sort by pathcode; emit order + cums ----------------
__global__ __launch_bounds__(256) void sort_kernel(
    const int* __restrict__ pc,
    int* __restrict__ order, int* __restrict__ gcums)
{
    __shared__ int hist[256];
    __shared__ int offs[256];
    __shared__ int cums[257];
    int tid = threadIdx.x;
    hist[tid] = 0;
    __syncthreads();

    int myPc[8];
    #pragma unroll
    for (int i = 0; i < 8; ++i) {
        int t = tid * 8 + i;
        myPc[i] = pc[t];
        atomicAdd(&hist[myPc[i] - 256], 1);
    }
    __syncthreads();

    if (tid < 64) {   // wave-0 exclusive scan over 256 bins (4 per lane)
        int lane = tid;
        int v0 = hist[lane * 4 + 0], v1 = hist[lane * 4 + 1];
        int v2 = hist[lane * 4 + 2], v3 = hist[lane * 4 + 3];
        int sum = v0 + v1 + v2 + v3;
        int scan = sum;
        #pragma unroll
        for (int off = 1; off < 64; off <<= 1) {
            int n = __shfl_up(scan, off);
            if (lane >= off) scan += n;
        }
        int excl = scan - sum;
        offs[lane * 4 + 0] = excl;
        offs[lane * 4 + 1] = excl + v0;
        offs[lane * 4 + 2] = excl + v0 + v1;
        offs[lane * 4 + 3] = excl + v0 + v1 + v2;
    }
    __syncthreads();

    cums[tid] = offs[tid];          // snapshot before scatter mutates offs
    if (tid == 0) cums[256] = T_TOKENS;
    __syncthreads();

    #pragma unroll
    for (int i = 0; i < 8; ++i) {
        int t = tid * 8 + i;
        int bin = myPc[i] - 256;
        int pos = atomicAdd(&offs[bin], 1);
        order[pos] = t;
    }

    gcums[tid] = cums[tid];
    if (tid == 0) gcums[256] = T_TOKENS;
}

// ---------------- Kernel 3: per-(node, 16-col strip) GEMM; B in registers; no LDS ----------------
// grid = 255 nodes x 4 blocks; block = 4 waves; wave wv -> strip (blockIdx&3)*4+wv.
// Wave loads w2[node] cols [strip*16, +16) x k[0,256) ONCE into 8 bf16x8 frags,
// then streams the node's tokens in 16-row m-tiles: A frags direct from bf16 x.
// w2 read exactly once device-wide (~67 MB). No LDS, no barriers, no atomics.
__global__ __launch_bounds__(256) void out_kernel(
    const unsigned short* __restrict__ xbf, const float* __restrict__ w2s,
    const float* __restrict__ b2s, const float* __restrict__ pw,
    const int* __restrict__ order, const int* __restrict__ gcums,
    float* __restrict__ lvlbuf)
{
    int node = blockIdx.x >> 2;                        // 0..254
    int wv = threadIdx.x >> 6, lane = threadIdx.x & 63;
    int strip = (blockIdx.x & 3) * 4 + wv;             // 0..15
    int colbase = strip * 16;
    int l15 = lane & 15, kg = lane >> 4;

    int q = node + 1;
    int lvl = 31 - __clz(q);
    int shift = 8 - lvl;
    int start = gcums[(q << shift) - 256];
    int end   = gcums[((q + 1) << shift) - 256];
    int cnt = end - start;
    if (cnt <= 0) return;

    // B fragments: bfr[ks][i] = w2[node][ks*32 + kg*8 + i][colbase + l15]
    const float* w2n = w2s + ((size_t)node << 16) + colbase + l15;
    bf16x8 bfr[8];
    #pragma unroll
    for (int ks = 0; ks < 8; ++ks) {
        const float* bp = w2n + (size_t)(ks * 32 + kg * 8) * DIM;
        float t0 = bp[0 * DIM], t1 = bp[1 * DIM], t2 = bp[2 * DIM], t3 = bp[3 * DIM];
        float t4 = bp[4 * DIM], t5 = bp[5 * DIM], t6 = bp[6 * DIM], t7 = bp[7 * DIM];
        bf16x8 v;
        v[0] = (short)f2bf(t0); v[1] = (short)f2bf(t1);
        v[2] = (short)f2bf(t2); v[3] = (short)f2bf(t3);
        v[4] = (short)f2bf(t4); v[5] = (short)f2bf(t5);
        v[6] = (short)f2bf(t6); v[7] = (short)f2bf(t7);
        bfr[ks] = v;
    }

    float bias = b2s[((size_t)node << 8) + colbase + l15];
    float* dst = lvlbuf + ((size_t)lvl << 19);   // 2048*256 per level

    int nmt = (cnt + 15) >> 4;
    for (int m = 0; m < nmt; ++m) {
        int rA = m * 16 + l15;
        int tA = order[start + (rA < cnt ? rA : cnt - 1)];
        const unsigned short* xp = xbf + ((size_t)tA << 8);

        f32x4 acc = {0.f, 0.f, 0.f, 0.f};
        #pragma unroll
        for (int ks = 0; ks < 8; ++ks) {
            bf16x8 afr = *reinterpret_cast<const bf16x8*>(xp + ks * 32 + kg * 8);
            acc = __builtin_amdgcn_mfma_f32_16x16x32_bf16(afr, bfr[ks], acc, 0, 0, 0);
        }

        #pragma unroll
        for (int j = 0; j < 4; ++j) {
            int r = m * 16 + kg * 4 + j;
            if (r < cnt) {
                int t = order[start + r];
                float w = pw[(size_t)t * NLEV + lvl];
                dst[((size_t)t << 8) + colbase + l15] = w * (acc[j] + bias);
            }
        }
    }
}

// ---------------- Kernel 4: reduce 8 level-buffers -> out ----------------
__global__ __launch_bounds__(256) void reduce_kernel(
    const float* __restrict__ lvlbuf, float* __restrict__ out)
{
    int idx = blockIdx.x * 256 + threadIdx.x;          // float4 index, < 131072
    const float4* lb = reinterpret_cast<const float4*>(lvlbuf);
    float4 s = lb[idx];
    #pragma unroll
    for (int l = 1; l < NLEV; ++l) {
        float4 v = lb[(size_t)l * 131072 + idx];
        s.x += v.x; s.y += v.y; s.z += v.z; s.w += v.w;
    }
    reinterpret_cast<float4*>(out)[idx] = s;
}

extern "C" void kernel_launch(void* const* d_in, const int* in_sizes, int n_in,
                              void* d_out, int out_size, void* d_ws, size_t ws_size,
                              hipStream_t stream) {
    const float* x   = (const float*)d_in[0];
    const float* w1s = (const float*)d_in[1];
    const float* b1s = (const float*)d_in[2];
    const float* w2s = (const float*)d_in[3];
    const float* b2s = (const float*)d_in[4];
    float* out = (float*)d_out;

    // workspace layout
    float* pw            = (float*)d_ws;                          // 64 KB
    int* pc              = (int*)(pw + T_TOKENS * NLEV);          // 8 KB
    int* order           = pc + T_TOKENS;                         // 8 KB
    int* gcums           = order + T_TOKENS;                      // 1028 B
    unsigned short* xbf  = (unsigned short*)((char*)d_ws + (256 << 10));  // 1 MB
    float* lvlbuf        = (float*)((char*)d_ws + (2 << 20));     // 16 MB

    route_kernel<<<T_TOKENS / 4, 256, 0, stream>>>(x, w1s, b1s, pw, pc, xbf);
    sort_kernel<<<1, 256, 0, stream>>>(pc, order, gcums);
    out_kernel<<<255 * 4, 256, 0, stream>>>(xbf, w2s, b2s, pw, order, gcums, lvlbuf);
    reduce_kernel<<<512, 256, 0, stream>>>(lvlbuf, out);
}

// Round 11
// 49.864 us; speedup vs baseline: 5.3984x; 5.3984x over previous
//
#include <hip/hip_runtime.h>
#include <hip/hip_bf16.h>

#define T_TOKENS 2048
#define DIM 256
#define NLEV 8

using bf16x8 = __attribute__((ext_vector_type(8))) short;
using f32x4  = __attribute__((ext_vector_type(4))) float;

__device__ __forceinline__ unsigned short f2bf(float f) {
    union { float f; unsigned u; } v; v.f = f;
    unsigned r = v.u + 0x7FFFu + ((v.u >> 16) & 1u);   // RNE
    return (unsigned short)(r >> 16);
}

// ---------------- Kernel 1: routing (exact fp32) + x -> bf16 conversion ----------------
__global__ __launch_bounds__(256) void route_kernel(
    const float* __restrict__ x, const float* __restrict__ w1s,
    const float* __restrict__ b1s,
    float* __restrict__ pw,            // [T][8]
    int*   __restrict__ pc,            // [T] pathcode in [256,511]
    unsigned short* __restrict__ xbf)  // [T][256] bf16
{
    int wave = threadIdx.x >> 6;
    int lane = threadIdx.x & 63;
    int t = blockIdx.x * 4 + wave;    // grid = 512 -> t < 2048

    const float4 xv = *reinterpret_cast<const float4*>(x + (size_t)t * DIM + lane * 4);

    ushort4 xb;
    xb.x = f2bf(xv.x); xb.y = f2bf(xv.y); xb.z = f2bf(xv.z); xb.w = f2bf(xv.w);
    *reinterpret_cast<ushort4*>(xbf + (size_t)t * DIM + lane * 4) = xb;

    int p = 1;
    float keep = 0.0f;
    #pragma unroll
    for (int lvl = 0; lvl < NLEV; ++lvl) {
        int node = p - 1;
        const float4 wv = *reinterpret_cast<const float4*>(w1s + (size_t)node * DIM + lane * 4);
        float s = xv.x * wv.x + xv.y * wv.y + xv.z * wv.z + xv.w * wv.w;
        #pragma unroll
        for (int off = 32; off; off >>= 1) s += __shfl_xor(s, off);
        float score = s + b1s[node];
        float a = fabsf(score);
        float g = a * 0.5f * (1.0f + erff(a * 0.70710678118654752f));  // exact GELU
        if (lane == lvl) keep = g;
        int choice = (score > 0.0f) ? 1 : 0;   // sign(0)->choice 0 matches ref
        p = 2 * p + choice;
    }
    if (lane < NLEV) pw[(size_t)t * NLEV + lane] = keep;
    if (lane == 0) pc[t] = p;
}

// ---------------- Kernel 2: counting sort + unit enumeration (1 block) ----------------
// Units: (node, <=64-token chunk of its contiguous sorted range). <=511 total.
__global__ __launch_bounds__(256) void sort_kernel(
    const int* __restrict__ pc,
    int* __restrict__ order, unsigned* __restrict__ units, int* __restrict__ ucount)
{
    __shared__ int hist[256];
    __shared__ int offs[256];
    __shared__ int cums[257];
    __shared__ int wpart[4];
    int tid = threadIdx.x;
    hist[tid] = 0;
    __syncthreads();

    int myPc[8];
    #pragma unroll
    for (int i = 0; i < 8; ++i) {
        int t = tid * 8 + i;
        myPc[i] = pc[t];
        atomicAdd(&hist[myPc[i] - 256], 1);
    }
    __syncthreads();

    if (tid < 64) {
        int lane = tid;
        int v0 = hist[lane * 4 + 0], v1 = hist[lane * 4 + 1];
        int v2 = hist[lane * 4 + 2], v3 = hist[lane * 4 + 3];
        int sum = v0 + v1 + v2 + v3;
        int scan = sum;
        #pragma unroll
        for (int off = 1; off < 64; off <<= 1) {
            int n = __shfl_up(scan, off);
            if (lane >= off) scan += n;
        }
        int excl = scan - sum;
        offs[lane * 4 + 0] = excl;
        offs[lane * 4 + 1] = excl + v0;
        offs[lane * 4 + 2] = excl + v0 + v1;
        offs[lane * 4 + 3] = excl + v0 + v1 + v2;
    }
    __syncthreads();

    cums[tid] = offs[tid];
    if (tid == 0) cums[256] = T_TOKENS;
    __syncthreads();

    #pragma unroll
    for (int i = 0; i < 8; ++i) {
        int t = tid * 8 + i;
        int bin = myPc[i] - 256;
        int pos = atomicAdd(&offs[bin], 1);
        order[pos] = t;
    }

    int nch = 0, s = 0, e = 0, l = 0;
    if (tid < 255) {
        int q = tid + 1;
        l = 31 - __clz(q);
        int shift = 8 - l;
        int lo = (q << shift) - 256;
        int hi = ((q + 1) << shift) - 256;
        s = cums[lo];
        e = cums[hi];
        nch = (e - s + 63) >> 6;
    }
    int lane = tid & 63, w = tid >> 6;
    int scan = nch;
    #pragma unroll
    for (int off = 1; off < 64; off <<= 1) {
        int n = __shfl_up(scan, off);
        if (lane >= off) scan += n;
    }
    if (lane == 63) wpart[w] = scan;
    __syncthreads();
    int pre = 0;
    for (int k = 0; k < w; ++k) pre += wpart[k];
    int base = pre + scan - nch;
    for (int j = 0; j < nch; ++j) {
        int st = s + j * 64;
        int c = e - st; if (c > 64) c = 64;
        units[base + j] = (unsigned)tid | ((unsigned)l << 8) |
                          ((unsigned)st << 11) | ((unsigned)c << 22);
    }
    if (tid == 255) *ucount = pre + scan;
}

// ---------------- Kernel 3: per-(unit, 16-col strip) wave GEMM; B in registers; no LDS ----------------
// grid = 512 units x 4 blocks; block = 4 waves; wave wv -> strip (blockIdx&3)*4+wv.
// Wave: B strip (256k x 16c) ONCE into 8 bf16x8 frags; <=4 m-tiles of 16 tokens,
// A direct from bf16 x with a 2-deep named-buffer pipeline. No LDS/barriers/atomics.
__global__ __launch_bounds__(256, 2) void out_kernel(
    const unsigned short* __restrict__ xbf, const float* __restrict__ w2s,
    const float* __restrict__ b2s, const float* __restrict__ pw,
    const int* __restrict__ order, const unsigned* __restrict__ units,
    const int* __restrict__ ucount, float* __restrict__ lvlbuf)
{
    int u = blockIdx.x >> 2;
    if (u >= *ucount) return;
    unsigned d = units[u];
    int node  = (int)(d & 255u);
    int lvl   = (int)((d >> 8) & 7u);
    int start = (int)((d >> 11) & 2047u);
    int cnt   = (int)((d >> 22) & 127u);

    int wv = threadIdx.x >> 6, lane = threadIdx.x & 63;
    int strip = (blockIdx.x & 3) * 4 + wv;   // 0..15
    int colbase = strip * 16;
    int l15 = lane & 15, kg = lane >> 4;

    // my lane's token per m-tile (row = m*16 + l15, clamped)
    int tok[4];
    #pragma unroll
    for (int m = 0; m < 4; ++m) {
        int r = m * 16 + l15;
        tok[m] = order[start + (r < cnt ? r : cnt - 1)];
    }

    // B fragments: bfr[ks][i] = w2[node][ks*32 + kg*8 + i][colbase + l15]
    const float* w2n = w2s + ((size_t)node << 16) + colbase + l15;
    bf16x8 bfr[8];
    #pragma unroll
    for (int ks = 0; ks < 8; ++ks) {
        const float* bp = w2n + (size_t)(ks * 32 + kg * 8) * DIM;
        float t0 = bp[0 * DIM], t1 = bp[1 * DIM], t2 = bp[2 * DIM], t3 = bp[3 * DIM];
        float t4 = bp[4 * DIM], t5 = bp[5 * DIM], t6 = bp[6 * DIM], t7 = bp[7 * DIM];
        bf16x8 v;
        v[0] = (short)f2bf(t0); v[1] = (short)f2bf(t1);
        v[2] = (short)f2bf(t2); v[3] = (short)f2bf(t3);
        v[4] = (short)f2bf(t4); v[5] = (short)f2bf(t5);
        v[6] = (short)f2bf(t6); v[7] = (short)f2bf(t7);
        bfr[ks] = v;
    }

    float bias = b2s[((size_t)node << 8) + colbase + l15];
    float* dst = lvlbuf + ((size_t)lvl << 19);   // 2048*256 per level
    int nmt = (cnt + 15) >> 4;

    bf16x8 aA[8], aB[8];
    auto loadA = [&](int m, bf16x8 (&a)[8]) {
        const unsigned short* xp = xbf + ((size_t)tok[m] << 8) + kg * 8;
        #pragma unroll
        for (int ks = 0; ks < 8; ++ks)
            a[ks] = *reinterpret_cast<const bf16x8*>(xp + ks * 32);
    };
    auto tile = [&](int m, const bf16x8 (&a)[8]) {
        f32x4 acc = {0.f, 0.f, 0.f, 0.f};
        #pragma unroll
        for (int ks = 0; ks < 8; ++ks)
            acc = __builtin_amdgcn_mfma_f32_16x16x32_bf16(a[ks], bfr[ks], acc, 0, 0, 0);
        #pragma unroll
        for (int j = 0; j < 4; ++j) {
            int r = m * 16 + kg * 4 + j;
            if (r < cnt) {
                int t = __shfl(tok[m], kg * 4 + j);
                float w = pw[(size_t)t * NLEV + lvl];
                dst[((size_t)t << 8) + colbase + l15] = w * (acc[j] + bias);
            }
        }
    };

    loadA(0, aA);
    if (nmt > 1) {
        loadA(1, aB);
        tile(0, aA);
        if (nmt > 2) {
            loadA(2, aA);
            tile(1, aB);
            if (nmt > 3) {
                loadA(3, aB);
                tile(2, aA);
                tile(3, aB);
            } else {
                tile(2, aA);
            }
        } else {
            tile(1, aB);
        }
    } else {
        tile(0, aA);
    }
}

// ---------------- Kernel 4: reduce 8 level-buffers -> out ----------------
__global__ __launch_bounds__(256) void reduce_kernel(
    const float* __restrict__ lvlbuf, float* __restrict__ out)
{
    int idx = blockIdx.x * 256 + threadIdx.x;          // float4 index, < 131072
    const float4* lb = reinterpret_cast<const float4*>(lvlbuf);
    float4 s = lb[idx];
    #pragma unroll
    for (int l = 1; l < NLEV; ++l) {
        float4 v = lb[(size_t)l * 131072 + idx];
        s.x += v.x; s.y += v.y; s.z += v.z; s.w += v.w;
    }
    reinterpret_cast<float4*>(out)[idx] = s;
}

extern "C" void kernel_launch(void* const* d_in, const int* in_sizes, int n_in,
                              void* d_out, int out_size, void* d_ws, size_t ws_size,
                              hipStream_t stream) {
    const float* x   = (const float*)d_in[0];
    const float* w1s = (const float*)d_in[1];
    const float* b1s = (const float*)d_in[2];
    const float* w2s = (const float*)d_in[3];
    const float* b2s = (const float*)d_in[4];
    float* out = (float*)d_out;

    // workspace layout
    float* pw            = (float*)d_ws;                          // 64 KB
    int* pc              = (int*)(pw + T_TOKENS * NLEV);          // 8 KB
    int* order           = pc + T_TOKENS;                         // 8 KB
    unsigned* units      = (unsigned*)(order + T_TOKENS);         // 2 KB
    int* ucount          = (int*)(units + 512);                   // 4 B
    unsigned short* xbf  = (unsigned short*)((char*)d_ws + (256 << 10));  // 1 MB
    float* lvlbuf        = (float*)((char*)d_ws + (2 << 20));     // 16 MB

    route_kernel<<<T_TOKENS / 4, 256, 0, stream>>>(x, w1s, b1s, pw, pc, xbf);
    sort_kernel<<<1, 256, 0, stream>>>(pc, order, units, ucount);
    out_kernel<<<2048, 256, 0, stream>>>(xbf, w2s, b2s, pw, order, units, ucount, lvlbuf);
    reduce_kernel<<<512, 256, 0, stream>>>(lvlbuf, out);
}